// Round 11
// baseline (159.895 us; speedup 1.0000x reference)
//
#include <hip/hip_runtime.h>
#include <hip/hip_bf16.h>

typedef __attribute__((ext_vector_type(8))) short bf16x8;
typedef __attribute__((ext_vector_type(4))) float f32x4;

__device__ __forceinline__ unsigned short f2bf(float f) {
    union { __hip_bfloat16 h; unsigned short u; } c;
    c.h = __float2bfloat16(f);
    return c.u;
}
__device__ __forceinline__ unsigned int pk2(float lo, float hi) {
    return (unsigned int)f2bf(lo) | ((unsigned int)f2bf(hi) << 16);
}
__device__ __forceinline__ bf16x8 as_bf(uint4 u) {
    union { uint4 a; bf16x8 b; } c; c.a = u; return c.b;
}
__device__ __forceinline__ float bf2f(unsigned short us) {
    return __uint_as_float(((unsigned int)us) << 16);
}
// async global->LDS, 16B/lane; lds dest = wave-uniform base + lane*16 (HW rule)
__device__ __forceinline__ void gload_lds16(const void* g, void* l) {
    __builtin_amdgcn_global_load_lds(
        (const __attribute__((address_space(1))) void*)g,
        (__attribute__((address_space(3))) void*)l, 16, 0, 0);
}

// ===================== prep: x->bf16 + means + gate/poly, weight pack, sym-bias =====================
__global__ __launch_bounds__(256) void prep_kernel(
    const float* __restrict__ x,
    const float* __restrict__ Wq, const float* __restrict__ Wkv, const float* __restrict__ Wproj,
    const float* __restrict__ Wgate, const float* __restrict__ bgate,
    const float* __restrict__ bias_table, const int* __restrict__ rel_index,
    unsigned short* __restrict__ xbf, int use_xbf,
    unsigned short* __restrict__ wq, unsigned short* __restrict__ wk,
    unsigned short* __restrict__ wv, unsigned short* __restrict__ wp,
    float* __restrict__ bsym, float* __restrict__ wpoly)
{
    const int bid = blockIdx.x, t = threadIdx.x;
    if (bid < 1024) {
        __shared__ float ps[8][256];
        __shared__ float mean_s[256];
        __shared__ float gsig[32];
        const int b = (bid & 7) * 128 + (bid >> 3);   // xcd = b>>7 matches attn's reader
        const float* xb = x + (size_t)b * 16384;
        if (use_xbf) {
            unsigned short* xo = xbf + (size_t)b * 16384;
            const int cg = t & 31, rr = t >> 5;
            float cs[8] = {};
            #pragma unroll
            for (int i = 0; i < 8; i++) {
                int row = rr * 8 + i;
                const float4* p = (const float4*)(xb + row * 256 + cg * 8);
                float4 f0 = p[0], f1 = p[1];
                uint4 u;
                u.x = pk2(f0.x, f0.y); u.y = pk2(f0.z, f0.w);
                u.z = pk2(f1.x, f1.y); u.w = pk2(f1.z, f1.w);
                *(uint4*)(xo + row * 256 + cg * 8) = u;
                cs[0] += f0.x; cs[1] += f0.y; cs[2] += f0.z; cs[3] += f0.w;
                cs[4] += f1.x; cs[5] += f1.y; cs[6] += f1.z; cs[7] += f1.w;
            }
            #pragma unroll
            for (int j = 0; j < 8; j++) ps[rr][cg * 8 + j] = cs[j];
            __syncthreads();
            float s = 0.f;
            #pragma unroll
            for (int r8 = 0; r8 < 8; r8++) s += ps[r8][t];
            mean_s[t] = s * (1.f / 64.f);
        } else {
            float s = 0.f;
            #pragma unroll 8
            for (int n = 0; n < 64; n++) s += xb[n * 256 + t];
            mean_s[t] = s * (1.f / 64.f);
        }
        __syncthreads();
        if (t < 32) {
            int h = t >> 2, j = t & 3;
            float g = bgate[j];
            #pragma unroll 8
            for (int dd = 0; dd < 32; dd++) g = fmaf(mean_s[h * 32 + dd], Wgate[dd * 4 + j], g);
            gsig[t] = 1.f / (1.f + __expf(-g));
        }
        __syncthreads();
        if (t < 8) {
            float g0 = gsig[t * 4], g1 = gsig[t * 4 + 1], g2 = gsig[t * 4 + 2], g3 = gsig[t * 4 + 3];
            float a = 0.125f * g3, bb = 0.375f * g0, cc = 0.375f * g1, dd = 0.125f * g2;
            float4 o;
            o.x = a + bb + cc + dd;
            o.y = 3.f * a + bb - cc - 3.f * dd;
            o.z = 3.f * a - bb - cc + 3.f * dd;
            o.w = a - bb + cc - dd;
            ((float4*)wpoly)[b * 8 + t] = o;
        }
    } else if (bid < 2048) {
        int e = (bid - 1024) * 256 + t;
        int m = e >> 16, r = e & 65535, o = r >> 8, kk = r & 255;
        float v; unsigned short* dst;
        if (m == 0)      { v = Wq[kk * 256 + o];        dst = wq; }
        else if (m == 1) { v = Wkv[kk * 512 + o];       dst = wk; }
        else if (m == 2) { v = Wkv[kk * 512 + 256 + o]; dst = wv; }
        else             { v = Wproj[kk * 256 + o];     dst = wp; }
        dst[o * 256 + kk] = f2bf(v);
    } else {
        int e = (bid - 2048) * 256 + t;
        int hh = e >> 12, ij = e & 4095;
        int i = ij >> 6, j = ij & 63;
        float bij = bias_table[rel_index[ij] * 8 + hh];
        float bji = bias_table[rel_index[j * 64 + i] * 8 + hh];
        bsym[hh * 4096 + ij] = 0.5f * (fmaxf(bij, 0.f) + fmaxf(bji, 0.f));
    }
}

// ===================== attention core: 2 heads per block, 8 waves =====================
// Waves w0-w3 = head h0 (roles q/k/v0/v1), w4-w7 = head h1 (same roles).
// Per-wave code identical to the proven R9 kernel (VGPR ~60); fixed costs
// (x staging, barriers, launch) amortize over 2 heads; 24 waves/CU (3 blocks x 8).
// *** Spill law: never set min-waves bound implying VGPR cap < 128.
// LDS map (bytes), tile[41472]:
//   stage xs [0,32768) (64 rows x 512B, swizzled)   -- dead after barrier B
//   q01 [0,8192): q both heads, slot ^= hl*4        -> Ab0 [0,8192) after D
//   k01 [8192,16384): k both heads, slot ^= hl*4    -> Ab1 [8192,16384) after D
//   vT0 [16384,20480), vT1 [20480,24576)
//   ua0 [24576,28672), ub0 [28672,32768)
//   ua1 [32768,36864), ub1 [36864,40960)
//   dn0 @40960, dn1 @41216 (64 f32 each)
template <bool XBF>
__global__ __launch_bounds__(512, 4) void attn_kernel(
    const float* __restrict__ x, const unsigned short* __restrict__ xbf,
    const float* __restrict__ bq, const float* __restrict__ bkv,
    const unsigned short* __restrict__ wq, const unsigned short* __restrict__ wk,
    const unsigned short* __restrict__ wv,
    const float* __restrict__ bsym, const float* __restrict__ wpoly,
    unsigned short* __restrict__ hid)
{
    __shared__ __align__(16) unsigned char tile[41472];

    const int bid = blockIdx.x;                 // 4096 blocks
    const int xcd = bid & 7, idx = bid >> 3;    // idx 0..511
    const int b = xcd * 128 + (idx >> 2);
    const int hp = idx & 3;                     // head-pair
    const int t = threadIdx.x;
    const int l = t & 63, w = t >> 6;           // 8 waves
    const int lr = l & 15, qg = l >> 4;
    const int hl = w >> 2;                      // head_local 0/1
    const int ws = w & 3;                       // role: 0=q 1=k 2,3=v halves
    const int h  = hp * 2 + hl;
    const int hs = hl << 2;                     // q/k slot xor per head

    const int AB = hl * 8192;                   // Ab region base
    const int VT = 16384 + hl * 4096;           // vT base
    const int UA = 24576 + hl * 8192;           // ua base
    const int UB = 28672 + hl * 8192;           // ub base
    float* dnp = (float*)(tile + 40960 + hl * 256);

    const float4 wv4 = ((const float4*)wpoly)[b * 8 + h];

    // ---- hoist weight B-fragments (issued before staging) ----
    uint4 Bfr0[8], Bfr1[8];
    {
        const unsigned short* wsel = (ws == 0) ? wq : (ws == 1) ? wk : wv;
        const uint4* Wp = (const uint4*)wsel;
        const int ct0 = (ws < 2) ? 0 : (ws - 2);
        const int o0 = h * 32 + ct0 * 16 + lr;
        #pragma unroll
        for (int ks = 0; ks < 8; ks++) Bfr0[ks] = Wp[o0 * 32 + ks * 4 + qg];
        if (ws < 2) {
            #pragma unroll
            for (int ks = 0; ks < 8; ks++) Bfr1[ks] = Wp[(o0 + 16) * 32 + ks * 4 + qg];
        }
    }

    // ---- phase 1: stage x[b] -> swizzled bf16 LDS (once per 2 heads) ----
    if (XBF) {
        const unsigned short* xb = xbf + (size_t)b * 16384;
        const int rp = l >> 5, u = l & 31;
        #pragma unroll
        for (int i = 0; i < 4; i++) {
            int row = i * 16 + w * 2 + rp;
            int csrc = (u & 24) | ((u & 7) ^ (row & 7));
            gload_lds16(xb + row * 256 + csrc * 8, tile + (i * 16 + w * 2) * 512);
        }
    } else {
        const float* xb = x + (size_t)b * 16384;
        #pragma unroll
        for (int i = 0; i < 4; i++) {
            int e = t + i * 512;
            int row = e >> 5, c = e & 31;
            const float4* p = (const float4*)(xb + row * 256 + c * 8);
            float4 f0 = p[0], f1 = p[1];
            uint4 u;
            u.x = pk2(f0.x, f0.y); u.y = pk2(f0.z, f0.w);
            u.z = pk2(f1.x, f1.y); u.w = pk2(f1.z, f1.w);
            *(uint4*)(tile + row * 512 + ((c >> 3) << 7) + (((c & 7) ^ (row & 7)) << 4)) = u;
        }
    }

    // bias-init accumulators
    f32x4 acc0[4], acc1[4];
    {
        const int ct0 = (ws < 2) ? 0 : (ws - 2);
        const int o0 = h * 32 + ct0 * 16 + lr;
        float b0 = (ws == 0) ? bq[o0] : (ws == 1) ? bkv[o0] : bkv[256 + o0];
        float b1 = (ws == 0) ? bq[o0 + 16] : (ws == 1) ? bkv[o0 + 16] : 0.f;
        #pragma unroll
        for (int mt = 0; mt < 4; mt++) {
            f32x4 z0 = {b0, b0, b0, b0}; acc0[mt] = z0;
            f32x4 z1 = {b1, b1, b1, b1}; acc1[mt] = z1;
        }
    }
    __syncthreads();   // A: x-tile staged

    // ---- phase 2: QKV MFMA ----
    __builtin_amdgcn_s_setprio(1);
    if (ws < 2) {
        #pragma unroll
        for (int mt = 0; mt < 4; mt++) {
            const int rowA = mt * 16 + lr;
            #pragma unroll
            for (int ks = 0; ks < 8; ks++) {
                const int c = ks * 4 + qg;
                bf16x8 af = *(const bf16x8*)(tile + rowA * 512 + ((c >> 3) << 7) + (((c & 7) ^ (rowA & 7)) << 4));
                acc0[mt] = __builtin_amdgcn_mfma_f32_16x16x32_bf16(af, as_bf(Bfr0[ks]), acc0[mt], 0, 0, 0);
                acc1[mt] = __builtin_amdgcn_mfma_f32_16x16x32_bf16(af, as_bf(Bfr1[ks]), acc1[mt], 0, 0, 0);
            }
        }
    } else {
        #pragma unroll
        for (int mt = 0; mt < 4; mt++) {
            const int rowA = mt * 16 + lr;
            #pragma unroll
            for (int ks = 0; ks < 8; ks++) {
                const int c = ks * 4 + qg;
                bf16x8 af = *(const bf16x8*)(tile + rowA * 512 + ((c >> 3) << 7) + (((c & 7) ^ (rowA & 7)) << 4));
                acc0[mt] = __builtin_amdgcn_mfma_f32_16x16x32_bf16(af, as_bf(Bfr0[ks]), acc0[mt], 0, 0, 0);
            }
        }
    }
    __builtin_amdgcn_s_setprio(0);
    __syncthreads();   // B: all reads of x-tile done

    // hoist bsym loads
    float bsv[4][4];
    {
        const float* bh_ = bsym + h * 4096;
        #pragma unroll
        for (int jt = 0; jt < 4; jt++)
            #pragma unroll
            for (int r = 0; r < 4; r++)
                bsv[jt][r] = bh_[(ws * 16 + qg * 4 + r) * 64 + jt * 16 + lr];
    }

    // ---- phase 3: row softmax for q (ws0) / k (ws1) ----
    if (ws < 2) {
        #pragma unroll
        for (int mt = 0; mt < 4; mt++)
            #pragma unroll
            for (int r = 0; r < 4; r++) {
                float e0 = __expf(acc0[mt][r]), e1 = __expf(acc1[mt][r]);
                float s = e0 + e1;
                s += __shfl_xor(s, 1); s += __shfl_xor(s, 2);
                s += __shfl_xor(s, 4); s += __shfl_xor(s, 8);
                float inv = 1.f / s;
                acc0[mt][r] = e0 * inv; acc1[mt][r] = e1 * inv;
            }
    }

    // ---- phase 4: spill q,k (slot^hs packed) and vT ----
    if (ws == 0) {
        #pragma unroll
        for (int mt = 0; mt < 4; mt++)
            #pragma unroll
            for (int r = 0; r < 4; r++) {
                int row = mt * 16 + qg * 4 + r;
                int d0 = lr, d1 = 16 + lr;
                *(short*)(tile + row * 128 + ((((d0 >> 3) ^ (row & 7)) ^ hs) << 4) + (d0 & 7) * 2) = (short)f2bf(acc0[mt][r]);
                *(short*)(tile + row * 128 + ((((d1 >> 3) ^ (row & 7)) ^ hs) << 4) + (d1 & 7) * 2) = (short)f2bf(acc1[mt][r]);
            }
    } else if (ws == 1) {
        #pragma unroll
        for (int mt = 0; mt < 4; mt++)
            #pragma unroll
            for (int r = 0; r < 4; r++) {
                int row = mt * 16 + qg * 4 + r;
                int d0 = lr, d1 = 16 + lr;
                *(short*)(tile + 8192 + row * 128 + ((((d0 >> 3) ^ (row & 7)) ^ hs) << 4) + (d0 & 7) * 2) = (short)f2bf(acc0[mt][r]);
                *(short*)(tile + 8192 + row * 128 + ((((d1 >> 3) ^ (row & 7)) ^ hs) << 4) + (d1 & 7) * 2) = (short)f2bf(acc1[mt][r]);
            }
    } else {
        const int d = (ws - 2) * 16 + lr;
        #pragma unroll
        for (int mt = 0; mt < 4; mt++)
            #pragma unroll
            for (int r = 0; r < 4; r++) {
                int row = mt * 16 + qg * 4 + r;
                *(short*)(tile + VT + d * 128 + (((row >> 3) ^ (d & 7)) << 4) + (row & 7) * 2) = (short)f2bf(acc0[mt][r]);
            }
    }
    __syncthreads();   // C: q,k,vT readable

    // ---- phase 5: S_sym + fused row-sums -> dn (4 waves per head, row-tile = ws) ----
    float sv[4][4];
    float dnv[4];
    {
        const int swz = ((qg ^ (lr & 7)) ^ hs) << 4;
        bf16x8 aqf = *(const bf16x8*)(tile + (ws * 16 + lr) * 128 + swz);
        bf16x8 akf = *(const bf16x8*)(tile + 8192 + (ws * 16 + lr) * 128 + swz);
        float rs[4] = {0.f, 0.f, 0.f, 0.f};
        __builtin_amdgcn_s_setprio(1);
        #pragma unroll
        for (int jt = 0; jt < 4; jt++) {
            bf16x8 bqf = *(const bf16x8*)(tile + (jt * 16 + lr) * 128 + swz);
            bf16x8 bkf = *(const bf16x8*)(tile + 8192 + (jt * 16 + lr) * 128 + swz);
            f32x4 qk = {0.f, 0.f, 0.f, 0.f}, kq = {0.f, 0.f, 0.f, 0.f};
            qk = __builtin_amdgcn_mfma_f32_16x16x32_bf16(aqf, bkf, qk, 0, 0, 0);
            kq = __builtin_amdgcn_mfma_f32_16x16x32_bf16(akf, bqf, kq, 0, 0, 0);
            #pragma unroll
            for (int r = 0; r < 4; r++) {
                float v = 0.5f * (qk[r] + kq[r]) + bsv[jt][r];
                sv[jt][r] = v;
                rs[r] += v;
            }
        }
        __builtin_amdgcn_s_setprio(0);
        #pragma unroll
        for (int r = 0; r < 4; r++) {
            float s = rs[r];
            s += __shfl_xor(s, 1); s += __shfl_xor(s, 2);
            s += __shfl_xor(s, 4); s += __shfl_xor(s, 8);
            dnv[r] = (s > 0.f) ? rsqrtf(s) : s;
        }
        if (lr == 0) {
            int base = ws * 16 + qg * 4;
            dnp[base + 0] = dnv[0]; dnp[base + 1] = dnv[1];
            dnp[base + 2] = dnv[2]; dnp[base + 3] = dnv[3];
        }
    }
    __syncthreads();   // D: dn ready; q/k dead -> Ab may overwrite

    // ---- phase 6: normalize in-register, spill Ab bf16 ----
    {
        float dnj[4];
        #pragma unroll
        for (int jt = 0; jt < 4; jt++) dnj[jt] = dnp[jt * 16 + lr];
        #pragma unroll
        for (int jt = 0; jt < 4; jt++)
            #pragma unroll
            for (int r = 0; r < 4; r++) {
                int i = ws * 16 + qg * 4 + r, j = jt * 16 + lr;
                *(short*)(tile + AB + i * 128 + (((j >> 3) ^ (i & 7)) << 4) + (j & 7) * 2)
                    = (short)f2bf(sv[jt][r] * dnv[r] * dnj[jt]);
            }
    }
    __syncthreads();   // E: Ab ready

    // ---- phases 7-9: y = w0 v + w1 Av + w2 A^2 v + w3 A^3 v ----
    const float w0c = wv4.x, w1c = wv4.y, w2c = wv4.z, w3c = wv4.w;
    f32x4 y[2];
    #pragma unroll
    for (int ct = 0; ct < 2; ct++)
        #pragma unroll
        for (int r = 0; r < 4; r++) {
            int row = ws * 16 + qg * 4 + r;
            int d = ct * 16 + lr;
            unsigned short us = *(unsigned short*)(tile + VT + d * 128 + (((row >> 3) ^ (d & 7)) << 4) + (row & 7) * 2);
            y[ct][r] = w0c * bf2f(us);
        }

#define AU_ROUND(SRC, DST, WC, WRITE) {                                                          \
    f32x4 u0 = {0.f,0.f,0.f,0.f}, u1 = {0.f,0.f,0.f,0.f};                                        \
    __builtin_amdgcn_s_setprio(1);                                                               \
    _Pragma("unroll")                                                                            \
    for (int ks2 = 0; ks2 < 2; ks2++) {                                                          \
        int c = ks2 * 4 + qg;                                                                    \
        bf16x8 af = *(const bf16x8*)(tile + AB + (ws * 16 + lr) * 128 + ((c ^ (lr & 7)) << 4));  \
        bf16x8 b0 = *(const bf16x8*)(tile + (SRC) + lr * 128 + ((c ^ (lr & 7)) << 4));           \
        bf16x8 b1 = *(const bf16x8*)(tile + (SRC) + (16 + lr) * 128 + ((c ^ (lr & 7)) << 4));    \
        u0 = __builtin_amdgcn_mfma_f32_16x16x32_bf16(af, b0, u0, 0, 0, 0);                       \
        u1 = __builtin_amdgcn_mfma_f32_16x16x32_bf16(af, b1, u1, 0, 0, 0);                       \
    }                                                                                            \
    __builtin_amdgcn_s_setprio(0);                                                               \
    y[0] += (WC) * u0; y[1] += (WC) * u1;                                                        \
    if (WRITE) {                                                                                 \
        _Pragma("unroll")                                                                        \
        for (int r = 0; r < 4; r++) {                                                            \
            int i = ws * 16 + qg * 4 + r;                                                        \
            *(short*)(tile + (DST) + lr * 128 + (((i >> 3) ^ (lr & 7)) << 4) + (i & 7) * 2) = (short)f2bf(u0[r]); \
            *(short*)(tile + (DST) + (16 + lr) * 128 + (((i >> 3) ^ (lr & 7)) << 4) + (i & 7) * 2) = (short)f2bf(u1[r]); \
        }                                                                                        \
    }                                                                                            \
    __syncthreads();                                                                             \
}
    AU_ROUND(VT, UA, w1c, 1)   // u1 = A v   -> ua
    AU_ROUND(UA, UB, w2c, 1)   // u2 = A u1  -> ub
    AU_ROUND(UB, 0,  w3c, 0)   // u3 = A u2
#undef AU_ROUND

    // ---- write hidden bf16 ----
    #pragma unroll
    for (int ct = 0; ct < 2; ct++)
        #pragma unroll
        for (int r = 0; r < 4; r++) {
            int row = ws * 16 + qg * 4 + r;
            int col = h * 32 + ct * 16 + lr;
            hid[((size_t)b * 64 + row) * 256 + col] = f2bf(y[ct][r]);
        }
}

// ===================== output projection: direct A-frag loads, no LDS =====================
__global__ __launch_bounds__(256) void proj_kernel(
    const unsigned short* __restrict__ hidden,
    const unsigned short* __restrict__ wp,
    const float* __restrict__ bproj,
    float* __restrict__ out)
{
    const int bid = blockIdx.x;
    const int rb = (bid & 7) * 64 + (bid >> 3);
    const int t = threadIdx.x, l = t & 63, w = t >> 6;
    const int lr = l & 15, qg = l >> 4;

    const unsigned short* hb = hidden + (size_t)rb * 128 * 256;

    bf16x8 af[2][8];
    #pragma unroll
    for (int rt = 0; rt < 2; rt++) {
        int row = w * 32 + rt * 16 + lr;
        #pragma unroll
        for (int ks = 0; ks < 8; ks++)
            af[rt][ks] = *(const bf16x8*)(hb + row * 256 + (ks * 4 + qg) * 8);
    }
    float bzv[16];
    #pragma unroll
    for (int ct = 0; ct < 16; ct++) bzv[ct] = bproj[ct * 16 + lr];

    const uint4* WP = (const uint4*)wp;
    #pragma unroll 2
    for (int ct = 0; ct < 16; ct++) {
        f32x4 a0 = {0.f, 0.f, 0.f, 0.f}, a1 = {0.f, 0.f, 0.f, 0.f};
        #pragma unroll
        for (int ks = 0; ks < 8; ks++) {
            bf16x8 bf = as_bf(WP[(ct * 16 + lr) * 32 + ks * 4 + qg]);
            a0 = __builtin_amdgcn_mfma_f32_16x16x32_bf16(af[0][ks], bf, a0, 0, 0, 0);
            a1 = __builtin_amdgcn_mfma_f32_16x16x32_bf16(af[1][ks], bf, a1, 0, 0, 0);
        }
        int colg = ct * 16 + lr;
        float bz = bzv[ct];
        #pragma unroll
        for (int r = 0; r < 4; r++) {
            int rowg = rb * 128 + w * 32 + qg * 4 + r;
            out[(size_t)rowg * 256 + colg] = a0[r] + bz;
            out[(size_t)(rowg + 16) * 256 + colg] = a1[r] + bz;
        }
    }
}

extern "C" void kernel_launch(void* const* d_in, const int* in_sizes, int n_in,
                              void* d_out, int out_size, void* d_ws, size_t ws_size,
                              hipStream_t stream) {
    const float* x          = (const float*)d_in[0];
    const float* Wq         = (const float*)d_in[1];
    const float* bq         = (const float*)d_in[2];
    const float* Wkv        = (const float*)d_in[3];
    const float* bkv        = (const float*)d_in[4];
    const float* Wgate      = (const float*)d_in[5];
    const float* bgate      = (const float*)d_in[6];
    const float* Wproj      = (const float*)d_in[7];
    const float* bproj      = (const float*)d_in[8];
    const float* bias_table = (const float*)d_in[9];
    const int*   rel_index  = (const int*)d_in[10];
    float* out = (float*)d_out;
    unsigned char* wsb = (unsigned char*)d_ws;

    const size_t HID   = 0;                    // 33,554,432 (hidden bf16)
    const size_t WQo   = 33554432;
    const size_t WKo   = WQo + 131072;
    const size_t WVo   = WKo + 131072;
    const size_t WPo   = WVo + 131072;
    const size_t BIASo = WPo + 131072;
    const size_t WPOLY = BIASo + 131072;
    const size_t XBFo  = WPOLY + 131072;       // 33,554,432 (x bf16) — optional
    const int use_xbf  = (ws_size >= XBFo + 33554432ull) ? 1 : 0;

    unsigned short* hid = (unsigned short*)(wsb + HID);
    unsigned short* wq  = (unsigned short*)(wsb + WQo);
    unsigned short* wk  = (unsigned short*)(wsb + WKo);
    unsigned short* wv  = (unsigned short*)(wsb + WVo);
    unsigned short* wp  = (unsigned short*)(wsb + WPo);
    float* bsym  = (float*)(wsb + BIASo);
    float* wpoly = (float*)(wsb + WPOLY);
    unsigned short* xbf = (unsigned short*)(wsb + XBFo);

    prep_kernel<<<dim3(2176), dim3(256), 0, stream>>>(
        x, Wq, Wkv, Wproj, Wgate, bgate, bias_table, rel_index,
        xbf, use_xbf, wq, wk, wv, wp, bsym, wpoly);
    if (use_xbf)
        attn_kernel<true><<<dim3(4096), dim3(512), 0, stream>>>(
            x, xbf, bq, bkv, wq, wk, wv, bsym, wpoly, hid);
    else
        attn_kernel<false><<<dim3(4096), dim3(512), 0, stream>>>(
            x, xbf, bq, bkv, wq, wk, wv, bsym, wpoly, hid);
    proj_kernel<<<dim3(512), dim3(256), 0, stream>>>(hid, wp, bproj, out);
}

// Round 12
// 145.083 us; speedup vs baseline: 1.1021x; 1.1021x over previous
//
#include <hip/hip_runtime.h>
#include <hip/hip_bf16.h>

typedef __attribute__((ext_vector_type(8))) short bf16x8;
typedef __attribute__((ext_vector_type(4))) float f32x4;

__device__ __forceinline__ unsigned short f2bf(float f) {
    union { __hip_bfloat16 h; unsigned short u; } c;
    c.h = __float2bfloat16(f);
    return c.u;
}
__device__ __forceinline__ unsigned int pk2(float lo, float hi) {
    return (unsigned int)f2bf(lo) | ((unsigned int)f2bf(hi) << 16);
}
__device__ __forceinline__ bf16x8 as_bf(uint4 u) {
    union { uint4 a; bf16x8 b; } c; c.a = u; return c.b;
}
__device__ __forceinline__ float bf2f(unsigned short us) {
    return __uint_as_float(((unsigned int)us) << 16);
}
// async global->LDS, 16B/lane; lds dest = wave-uniform base + lane*16 (HW rule)
__device__ __forceinline__ void gload_lds16(const void* g, void* l) {
    __builtin_amdgcn_global_load_lds(
        (const __attribute__((address_space(1))) void*)g,
        (__attribute__((address_space(3))) void*)l, 16, 0, 0);
}

// ===================== prep: x->bf16 + means + gate/poly, weight pack, sym-bias =====================
__global__ __launch_bounds__(256) void prep_kernel(
    const float* __restrict__ x,
    const float* __restrict__ Wq, const float* __restrict__ Wkv, const float* __restrict__ Wproj,
    const float* __restrict__ Wgate, const float* __restrict__ bgate,
    const float* __restrict__ bias_table, const int* __restrict__ rel_index,
    unsigned short* __restrict__ xbf, int use_xbf,
    unsigned short* __restrict__ wq, unsigned short* __restrict__ wk,
    unsigned short* __restrict__ wv, unsigned short* __restrict__ wp,
    float* __restrict__ bsym, float* __restrict__ wpoly)
{
    const int bid = blockIdx.x, t = threadIdx.x;
    if (bid < 1024) {
        __shared__ float mean_s[256];
        __shared__ float gsig[32];
        const float* xb = x + (size_t)bid * 16384;
        float s = 0.f;
        if (use_xbf) {
            unsigned short* xo = xbf + (size_t)bid * 16384;
            #pragma unroll 4
            for (int n = 0; n < 64; n++) { float v = xb[n * 256 + t]; s += v; xo[n * 256 + t] = f2bf(v); }
        } else {
            #pragma unroll 8
            for (int n = 0; n < 64; n++) s += xb[n * 256 + t];
        }
        mean_s[t] = s * (1.f / 64.f);
        __syncthreads();
        if (t < 32) {
            int h = t >> 2, j = t & 3;
            float g = bgate[j];
            #pragma unroll 8
            for (int dd = 0; dd < 32; dd++) g = fmaf(mean_s[h * 32 + dd], Wgate[dd * 4 + j], g);
            gsig[t] = 1.f / (1.f + __expf(-g));
        }
        __syncthreads();
        if (t < 8) {
            float g0 = gsig[t * 4], g1 = gsig[t * 4 + 1], g2 = gsig[t * 4 + 2], g3 = gsig[t * 4 + 3];
            float a = 0.125f * g3, bb = 0.375f * g0, cc = 0.375f * g1, dd = 0.125f * g2;
            float4 o;
            o.x = a + bb + cc + dd;
            o.y = 3.f * a + bb - cc - 3.f * dd;
            o.z = 3.f * a - bb - cc + 3.f * dd;
            o.w = a - bb + cc - dd;
            ((float4*)wpoly)[bid * 8 + t] = o;
        }
    } else if (bid < 2048) {
        // transpose-pack 4 weight matrices to bf16: dst[o][k] = src[k][o]
        int e = (bid - 1024) * 256 + t;
        int m = e >> 16, r = e & 65535, o = r >> 8, kk = r & 255;
        float v; unsigned short* dst;
        if (m == 0)      { v = Wq[kk * 256 + o];        dst = wq; }
        else if (m == 1) { v = Wkv[kk * 512 + o];       dst = wk; }
        else if (m == 2) { v = Wkv[kk * 512 + 256 + o]; dst = wv; }
        else             { v = Wproj[kk * 256 + o];     dst = wp; }
        dst[o * 256 + kk] = f2bf(v);
    } else {
        // symmetric pre-relu positional bias: bsym[h][i*64+j] = (relu(b_ij)+relu(b_ji))/2
        int e = (bid - 2048) * 256 + t;
        int hh = e >> 12, ij = e & 4095;
        int i = ij >> 6, j = ij & 63;
        float bij = bias_table[rel_index[ij] * 8 + hh];
        float bji = bias_table[rel_index[j * 64 + i] * 8 + hh];
        bsym[hh * 4096 + ij] = 0.5f * (fmaxf(bij, 0.f) + fmaxf(bji, 0.f));
    }
}

// ===================== attention core (R9 structure, merged polynomial tail) =====================
// block = one (b,h); 4 waves, QKV role split: w0=q, w1=k, w2/w3=v halves.
// XCD-chunked swizzle: xcd=bid&7 owns b in [xcd*128, xcd*128+128), heads adjacent.
// LDS = 32 KB whole-x staging. launch_bounds(256,4): VGPR cap 128.
// *** Spill law: NEVER raise min-waves above 4 (R5/R7: 200-500 MB scratch).
// *** Split-K staging (R7/R8) and 2-head fusion (R11) both regressed — do not reintroduce.
// Polynomial tail uses symmetry of normalized A: Asq = A·A computed alongside u1 = A·v,
// then u2 = Asq·v and u3 = Asq·u1 in ONE phase -> barriers 8 -> 6, ub round-trip gone.
// tile map: stage xs [0,32K). post-QKV: Ab/q[0,8K); k[8K,16K) -> Asq after E;
//           vT[16K,20K); ua[20K,24K); dn f32[64] @28672
template <bool XBF>
__global__ __launch_bounds__(256, 4) void attn_kernel(
    const float* __restrict__ x, const unsigned short* __restrict__ xbf,
    const float* __restrict__ bq, const float* __restrict__ bkv,
    const unsigned short* __restrict__ wq, const unsigned short* __restrict__ wk,
    const unsigned short* __restrict__ wv,
    const float* __restrict__ bsym, const float* __restrict__ wpoly,
    unsigned short* __restrict__ hid)
{
    __shared__ __align__(16) unsigned char tile[32768];
    float* dn = (float*)(tile + 28672);

    const int bid = blockIdx.x;
    const int xcd = bid & 7, idx = bid >> 3;
    const int b = xcd * 128 + (idx >> 3), h = idx & 7;
    const int t = threadIdx.x;
    const int l = t & 63, w = t >> 6;
    const int lr = l & 15, qg = l >> 4;

    const float4 wv4 = ((const float4*)wpoly)[b * 8 + h];

    // ---- hoist weight B-fragments (issued before staging) ----
    const int role = w;                      // 0=q, 1=k, 2=v(d 0..15), 3=v(d 16..31)
    uint4 Bfr0[8], Bfr1[8];
    {
        const unsigned short* wsel = (role == 0) ? wq : (role == 1) ? wk : wv;
        const uint4* Wp = (const uint4*)wsel;
        const int ct0 = (role < 2) ? 0 : (role - 2);
        const int o0 = h * 32 + ct0 * 16 + lr;
        #pragma unroll
        for (int ks = 0; ks < 8; ks++) Bfr0[ks] = Wp[o0 * 32 + ks * 4 + qg];
        if (role < 2) {
            #pragma unroll
            for (int ks = 0; ks < 8; ks++) Bfr1[ks] = Wp[(o0 + 16) * 32 + ks * 4 + qg];
        }
    }

    // ---- phase 1: stage x[b] -> swizzled bf16 LDS ----
    if (XBF) {
        const unsigned short* xb = xbf + (size_t)b * 16384;
        const int rp = l >> 5, u = l & 31;
        #pragma unroll
        for (int i = 0; i < 8; i++) {
            int row = i * 8 + w * 2 + rp;
            int csrc = (u & 24) | ((u & 7) ^ (row & 7));   // inverse of reader swizzle (involution)
            gload_lds16(xb + row * 256 + csrc * 8, tile + (i * 8 + w * 2) * 512);
        }
    } else {
        const float* xb = x + (size_t)b * 16384;
        #pragma unroll
        for (int i = 0; i < 8; i++) {
            int e = t + i * 256;
            int row = e >> 5, c = e & 31;
            const float4* p = (const float4*)(xb + row * 256 + c * 8);
            float4 f0 = p[0], f1 = p[1];
            uint4 u;
            u.x = pk2(f0.x, f0.y); u.y = pk2(f0.z, f0.w);
            u.z = pk2(f1.x, f1.y); u.w = pk2(f1.z, f1.w);
            *(uint4*)(tile + row * 512 + ((c >> 3) << 7) + (((c & 7) ^ (row & 7)) << 4)) = u;
        }
    }

    // bias-init accumulators
    f32x4 acc0[4], acc1[4];
    {
        const int ct0 = (role < 2) ? 0 : (role - 2);
        const int o0 = h * 32 + ct0 * 16 + lr;
        float b0 = (role == 0) ? bq[o0] : (role == 1) ? bkv[o0] : bkv[256 + o0];
        float b1 = (role == 0) ? bq[o0 + 16] : (role == 1) ? bkv[o0 + 16] : 0.f;
        #pragma unroll
        for (int mt = 0; mt < 4; mt++) {
            f32x4 z0 = {b0, b0, b0, b0}; acc0[mt] = z0;
            f32x4 z1 = {b1, b1, b1, b1}; acc1[mt] = z1;
        }
    }
    __syncthreads();   // A: x-tile staged

    // ---- phase 2: QKV MFMA, zero global loads in loop ----
    __builtin_amdgcn_s_setprio(1);
    if (role < 2) {
        #pragma unroll
        for (int mt = 0; mt < 4; mt++) {
            const int rowA = mt * 16 + lr;
            #pragma unroll
            for (int ks = 0; ks < 8; ks++) {
                const int c = ks * 4 + qg;
                bf16x8 af = *(const bf16x8*)(tile + rowA * 512 + ((c >> 3) << 7) + (((c & 7) ^ (rowA & 7)) << 4));
                acc0[mt] = __builtin_amdgcn_mfma_f32_16x16x32_bf16(af, as_bf(Bfr0[ks]), acc0[mt], 0, 0, 0);
                acc1[mt] = __builtin_amdgcn_mfma_f32_16x16x32_bf16(af, as_bf(Bfr1[ks]), acc1[mt], 0, 0, 0);
            }
        }
    } else {
        #pragma unroll
        for (int mt = 0; mt < 4; mt++) {
            const int rowA = mt * 16 + lr;
            #pragma unroll
            for (int ks = 0; ks < 8; ks++) {
                const int c = ks * 4 + qg;
                bf16x8 af = *(const bf16x8*)(tile + rowA * 512 + ((c >> 3) << 7) + (((c & 7) ^ (rowA & 7)) << 4));
                acc0[mt] = __builtin_amdgcn_mfma_f32_16x16x32_bf16(af, as_bf(Bfr0[ks]), acc0[mt], 0, 0, 0);
            }
        }
    }
    __builtin_amdgcn_s_setprio(0);
    __syncthreads();   // B: all reads of x-tile done

    // hoist bsym loads (L2-latency hides under softmax+spill)
    float bsv[4][4];
    {
        const float* bh_ = bsym + h * 4096;
        #pragma unroll
        for (int jt = 0; jt < 4; jt++)
            #pragma unroll
            for (int r = 0; r < 4; r++)
                bsv[jt][r] = bh_[(w * 16 + qg * 4 + r) * 64 + jt * 16 + lr];
    }

    // ---- phase 3: row softmax for q (wave0) / k (wave1), no max-subtraction ----
    if (role < 2) {
        #pragma unroll
        for (int mt = 0; mt < 4; mt++)
            #pragma unroll
            for (int r = 0; r < 4; r++) {
                float e0 = __expf(acc0[mt][r]), e1 = __expf(acc1[mt][r]);
                float s = e0 + e1;
                s += __shfl_xor(s, 1); s += __shfl_xor(s, 2);
                s += __shfl_xor(s, 4); s += __shfl_xor(s, 8);
                float inv = 1.f / s;
                acc0[mt][r] = e0 * inv; acc1[mt][r] = e1 * inv;
            }
    }

    // ---- phase 4: spill q,k (row-major swizzled) and vT ----
    if (role == 0) {
        #pragma unroll
        for (int mt = 0; mt < 4; mt++)
            #pragma unroll
            for (int r = 0; r < 4; r++) {
                int row = mt * 16 + qg * 4 + r;
                int d0 = lr, d1 = 16 + lr;
                *(short*)(tile + row * 128 + (((d0 >> 3) ^ (row & 7)) << 4) + (d0 & 7) * 2) = (short)f2bf(acc0[mt][r]);
                *(short*)(tile + row * 128 + (((d1 >> 3) ^ (row & 7)) << 4) + (d1 & 7) * 2) = (short)f2bf(acc1[mt][r]);
            }
    } else if (role == 1) {
        #pragma unroll
        for (int mt = 0; mt < 4; mt++)
            #pragma unroll
            for (int r = 0; r < 4; r++) {
                int row = mt * 16 + qg * 4 + r;
                int d0 = lr, d1 = 16 + lr;
                *(short*)(tile + 8192 + row * 128 + (((d0 >> 3) ^ (row & 7)) << 4) + (d0 & 7) * 2) = (short)f2bf(acc0[mt][r]);
                *(short*)(tile + 8192 + row * 128 + (((d1 >> 3) ^ (row & 7)) << 4) + (d1 & 7) * 2) = (short)f2bf(acc1[mt][r]);
            }
    } else {
        const int d = (role - 2) * 16 + lr;
        #pragma unroll
        for (int mt = 0; mt < 4; mt++)
            #pragma unroll
            for (int r = 0; r < 4; r++) {
                int row = mt * 16 + qg * 4 + r;
                *(short*)(tile + 16384 + d * 128 + (((row >> 3) ^ (d & 7)) << 4) + (row & 7) * 2) = (short)f2bf(acc0[mt][r]);
            }
    }
    __syncthreads();   // C: q,k,vT readable

    // ---- phase 5: S_sym = (qk^T + (qk^T)^T)/2 + bsym, fused row-sums -> dn ----
    float sv[4][4];
    float dnv[4];
    {
        const int swz = (qg ^ (lr & 7)) << 4;
        bf16x8 aqf = *(const bf16x8*)(tile + (w * 16 + lr) * 128 + swz);
        bf16x8 akf = *(const bf16x8*)(tile + 8192 + (w * 16 + lr) * 128 + swz);
        float rs[4] = {0.f, 0.f, 0.f, 0.f};
        __builtin_amdgcn_s_setprio(1);
        #pragma unroll
        for (int jt = 0; jt < 4; jt++) {
            bf16x8 bqf = *(const bf16x8*)(tile + (jt * 16 + lr) * 128 + swz);
            bf16x8 bkf = *(const bf16x8*)(tile + 8192 + (jt * 16 + lr) * 128 + swz);
            f32x4 qk = {0.f, 0.f, 0.f, 0.f}, kq = {0.f, 0.f, 0.f, 0.f};
            qk = __builtin_amdgcn_mfma_f32_16x16x32_bf16(aqf, bkf, qk, 0, 0, 0);
            kq = __builtin_amdgcn_mfma_f32_16x16x32_bf16(akf, bqf, kq, 0, 0, 0);
            #pragma unroll
            for (int r = 0; r < 4; r++) {
                float v = 0.5f * (qk[r] + kq[r]) + bsv[jt][r];
                sv[jt][r] = v;
                rs[r] += v;
            }
        }
        __builtin_amdgcn_s_setprio(0);
        #pragma unroll
        for (int r = 0; r < 4; r++) {
            float s = rs[r];
            s += __shfl_xor(s, 1); s += __shfl_xor(s, 2);
            s += __shfl_xor(s, 4); s += __shfl_xor(s, 8);
            dnv[r] = (s > 0.f) ? rsqrtf(s) : s;
        }
        if (lr == 0) {
            int base = w * 16 + qg * 4;
            dn[base + 0] = dnv[0]; dn[base + 1] = dnv[1];
            dn[base + 2] = dnv[2]; dn[base + 3] = dnv[3];
        }
    }
    __syncthreads();   // D: dn ready; q/k reads done -> Ab may overwrite q region

    // ---- phase 6: normalize in-register, spill Ab bf16 (overlays q region) ----
    {
        float dnj[4];
        #pragma unroll
        for (int jt = 0; jt < 4; jt++) dnj[jt] = dn[jt * 16 + lr];
        #pragma unroll
        for (int jt = 0; jt < 4; jt++)
            #pragma unroll
            for (int r = 0; r < 4; r++) {
                int i = w * 16 + qg * 4 + r, j = jt * 16 + lr;
                *(short*)(tile + i * 128 + (((j >> 3) ^ (i & 7)) << 4) + (j & 7) * 2)
                    = (short)f2bf(sv[jt][r] * dnv[r] * dnj[jt]);
            }
    }
    __syncthreads();   // E: Ab ready

    // ---- y init: y = w0 * v ----
    const float w0c = wv4.x, w1c = wv4.y, w2c = wv4.z, w3c = wv4.w;
    f32x4 y[2];
    #pragma unroll
    for (int ct = 0; ct < 2; ct++)
        #pragma unroll
        for (int r = 0; r < 4; r++) {
            int row = w * 16 + qg * 4 + r;
            int d = ct * 16 + lr;
            unsigned short us = *(unsigned short*)(tile + 16384 + d * 128 + (((row >> 3) ^ (d & 7)) << 4) + (row & 7) * 2);
            y[ct][r] = w0c * bf2f(us);
        }

    // ---- phase 7: u1 = A·v (-> ua) AND Asq = A·A (-> k region; A symmetric so
    //      row-major Ab doubles as the B operand via the vT-read pattern) ----
    {
        f32x4 u1a = {0.f,0.f,0.f,0.f}, u1b = {0.f,0.f,0.f,0.f};
        f32x4 sq[4];
        #pragma unroll
        for (int jt = 0; jt < 4; jt++) { f32x4 z = {0.f,0.f,0.f,0.f}; sq[jt] = z; }
        __builtin_amdgcn_s_setprio(1);
        #pragma unroll
        for (int ks2 = 0; ks2 < 2; ks2++) {
            int c = ks2 * 4 + qg;
            int so = (c ^ (lr & 7)) << 4;
            bf16x8 af = *(const bf16x8*)(tile + (w * 16 + lr) * 128 + so);
            bf16x8 v0 = *(const bf16x8*)(tile + 16384 + lr * 128 + so);
            bf16x8 v1 = *(const bf16x8*)(tile + 16384 + (16 + lr) * 128 + so);
            u1a = __builtin_amdgcn_mfma_f32_16x16x32_bf16(af, v0, u1a, 0, 0, 0);
            u1b = __builtin_amdgcn_mfma_f32_16x16x32_bf16(af, v1, u1b, 0, 0, 0);
            bf16x8 b0 = *(const bf16x8*)(tile + lr * 128 + so);
            bf16x8 b1 = *(const bf16x8*)(tile + (16 + lr) * 128 + so);
            bf16x8 b2 = *(const bf16x8*)(tile + (32 + lr) * 128 + so);
            bf16x8 b3 = *(const bf16x8*)(tile + (48 + lr) * 128 + so);
            sq[0] = __builtin_amdgcn_mfma_f32_16x16x32_bf16(af, b0, sq[0], 0, 0, 0);
            sq[1] = __builtin_amdgcn_mfma_f32_16x16x32_bf16(af, b1, sq[1], 0, 0, 0);
            sq[2] = __builtin_amdgcn_mfma_f32_16x16x32_bf16(af, b2, sq[2], 0, 0, 0);
            sq[3] = __builtin_amdgcn_mfma_f32_16x16x32_bf16(af, b3, sq[3], 0, 0, 0);
        }
        __builtin_amdgcn_s_setprio(0);
        y[0] += w1c * u1a; y[1] += w1c * u1b;
        // spill u1 transposed -> ua [20480]
        #pragma unroll
        for (int r = 0; r < 4; r++) {
            int i = w * 16 + qg * 4 + r;
            *(short*)(tile + 20480 + lr * 128 + (((i >> 3) ^ (lr & 7)) << 4) + (i & 7) * 2) = (short)f2bf(u1a[r]);
            *(short*)(tile + 20480 + (16 + lr) * 128 + (((i >> 3) ^ (lr & 7)) << 4) + (i & 7) * 2) = (short)f2bf(u1b[r]);
        }
        // spill Asq row-major (Ab swizzle) -> k region [8192]
        #pragma unroll
        for (int jt = 0; jt < 4; jt++)
            #pragma unroll
            for (int r = 0; r < 4; r++) {
                int i = w * 16 + qg * 4 + r, j = jt * 16 + lr;
                *(short*)(tile + 8192 + i * 128 + (((j >> 3) ^ (i & 7)) << 4) + (j & 7) * 2) = (short)f2bf(sq[jt][r]);
            }
    }
    __syncthreads();   // F: ua + Asq ready

    // ---- phase 8: u2 = Asq·v, u3 = Asq·u1 in one pass; no trailing barrier ----
    {
        f32x4 u2a = {0.f,0.f,0.f,0.f}, u2b = {0.f,0.f,0.f,0.f};
        f32x4 u3a = {0.f,0.f,0.f,0.f}, u3b = {0.f,0.f,0.f,0.f};
        __builtin_amdgcn_s_setprio(1);
        #pragma unroll
        for (int ks2 = 0; ks2 < 2; ks2++) {
            int c = ks2 * 4 + qg;
            int so = (c ^ (lr & 7)) << 4;
            bf16x8 af = *(const bf16x8*)(tile + 8192 + (w * 16 + lr) * 128 + so);
            bf16x8 v0 = *(const bf16x8*)(tile + 16384 + lr * 128 + so);
            bf16x8 v1 = *(const bf16x8*)(tile + 16384 + (16 + lr) * 128 + so);
            bf16x8 a0 = *(const bf16x8*)(tile + 20480 + lr * 128 + so);
            bf16x8 a1 = *(const bf16x8*)(tile + 20480 + (16 + lr) * 128 + so);
            u2a = __builtin_amdgcn_mfma_f32_16x16x32_bf16(af, v0, u2a, 0, 0, 0);
            u2b = __builtin_amdgcn_mfma_f32_16x16x32_bf16(af, v1, u2b, 0, 0, 0);
            u3a = __builtin_amdgcn_mfma_f32_16x16x32_bf16(af, a0, u3a, 0, 0, 0);
            u3b = __builtin_amdgcn_mfma_f32_16x16x32_bf16(af, a1, u3b, 0, 0, 0);
        }
        __builtin_amdgcn_s_setprio(0);
        y[0] += w2c * u2a + w3c * u3a;
        y[1] += w2c * u2b + w3c * u3b;
    }

    // ---- write hidden bf16 ----
    #pragma unroll
    for (int ct = 0; ct < 2; ct++)
        #pragma unroll
        for (int r = 0; r < 4; r++) {
            int row = w * 16 + qg * 4 + r;
            int col = h * 32 + ct * 16 + lr;
            hid[((size_t)b * 64 + row) * 256 + col] = f2bf(y[ct][r]);
        }
}

// ===================== output projection: 128 x 256 tile, hidden read once =====================
__global__ __launch_bounds__(256) void proj_kernel(
    const unsigned short* __restrict__ hidden,
    const unsigned short* __restrict__ wp,
    const float* __restrict__ bproj,
    float* __restrict__ out)
{
    __shared__ __align__(16) unsigned char atile[65536];
    const int rb = blockIdx.x;
    const int t = threadIdx.x, l = t & 63, w = t >> 6;
    const int lr = l & 15, qg = l >> 4;

    const unsigned short* hb = hidden + (size_t)rb * 128 * 256;
    {
        const int rp = l >> 5, u = l & 31;
        #pragma unroll
        for (int i = 0; i < 16; i++) {
            int row = i * 8 + w * 2 + rp;
            int csrc = (u & 24) | ((u & 7) ^ (row & 7));
            gload_lds16(hb + row * 256 + csrc * 8, atile + (i * 8 + w * 2) * 512);
        }
    }
    float bzv[16];
    #pragma unroll
    for (int ct = 0; ct < 16; ct++) bzv[ct] = bproj[ct * 16 + lr];
    __syncthreads();

    // hoist A fragments: 2 row-tiles x 8 k-steps
    bf16x8 af[2][8];
    #pragma unroll
    for (int rt = 0; rt < 2; rt++) {
        int row = w * 32 + rt * 16 + lr;
        #pragma unroll
        for (int ks = 0; ks < 8; ks++) {
            int c = ks * 4 + qg;
            af[rt][ks] = *(const bf16x8*)(atile + row * 512 + (((c & 24) | ((c & 7) ^ (row & 7))) << 4));
        }
    }

    const uint4* WP = (const uint4*)wp;
    #pragma unroll 2
    for (int ct = 0; ct < 16; ct++) {
        f32x4 a0 = {0.f, 0.f, 0.f, 0.f}, a1 = {0.f, 0.f, 0.f, 0.f};
        #pragma unroll
        for (int ks = 0; ks < 8; ks++) {
            bf16x8 bf = as_bf(WP[(ct * 16 + lr) * 32 + ks * 4 + qg]);
            a0 = __builtin_amdgcn_mfma_f32_16x16x32_bf16(af[0][ks], bf, a0, 0, 0, 0);
            a1 = __builtin_amdgcn_mfma_f32_16x16x32_bf16(af[1][ks], bf, a1, 0, 0, 0);
        }
        int colg = ct * 16 + lr;
        float bz = bzv[ct];
        #pragma unroll
        for (int r = 0; r < 4; r++) {
            int rowg = rb * 128 + w * 32 + qg * 4 + r;
            out[(size_t)rowg * 256 + colg] = a0[r] + bz;
            out[(size_t)(rowg + 16) * 256 + colg] = a1[r] + bz;
        }
    }
}

extern "C" void kernel_launch(void* const* d_in, const int* in_sizes, int n_in,
                              void* d_out, int out_size, void* d_ws, size_t ws_size,
                              hipStream_t stream) {
    const float* x          = (const float*)d_in[0];
    const float* Wq         = (const float*)d_in[1];
    const float* bq         = (const float*)d_in[2];
    const float* Wkv        = (const float*)d_in[3];
    const float* bkv        = (const float*)d_in[4];
    const float* Wgate      = (const float*)d_in[5];
    const float* bgate      = (const float*)d_in[6];
    const float* Wproj      = (const float*)d_in[7];
    const float* bproj      = (const float*)d_in[8];
    const float* bias_table = (const float*)d_in[9];
    const int*   rel_index  = (const int*)d_in[10];
    float* out = (float*)d_out;
    unsigned char* wsb = (unsigned char*)d_ws;

    // ws layout (bytes)
    const size_t HID   = 0;                    // 33,554,432 (hidden bf16)
    const size_t WQo   = 33554432;             // 131072 each
    const size_t WKo   = WQo + 131072;
    const size_t WVo   = WKo + 131072;
    const size_t WPo   = WVo + 131072;
    const size_t BIASo = WPo + 131072;         // 131072 (bsym f32 [8][64][64])
    const size_t WPOLY = BIASo + 131072;       // 131072
    const size_t XBFo  = WPOLY + 131072;       // 33,554,432 (x bf16) — optional
    const int use_xbf  = (ws_size >= XBFo + 33554432ull) ? 1 : 0;

    unsigned short* hid = (unsigned short*)(wsb + HID);
    unsigned short* wq  = (unsigned short*)(wsb + WQo);
    unsigned short* wk  = (unsigned short*)(wsb + WKo);
    unsigned short* wv  = (unsigned short*)(wsb + WVo);
    unsigned short* wp  = (unsigned short*)(wsb + WPo);
    float* bsym  = (float*)(wsb + BIASo);
    float* wpoly = (float*)(wsb + WPOLY);
    unsigned short* xbf = (unsigned short*)(wsb + XBFo);

    prep_kernel<<<dim3(2176), dim3(256), 0, stream>>>(
        x, Wq, Wkv, Wproj, Wgate, bgate, bias_table, rel_index,
        xbf, use_xbf, wq, wk, wv, wp, bsym, wpoly);
    if (use_xbf)
        attn_kernel<true><<<dim3(8192), dim3(256), 0, stream>>>(
            x, xbf, bq, bkv, wq, wk, wv, bsym, wpoly, hid);
    else
        attn_kernel<false><<<dim3(8192), dim3(256), 0, stream>>>(
            x, xbf, bq, bkv, wq, wk, wv, bsym, wpoly, hid);
    proj_kernel<<<dim3(512), dim3(256), 0, stream>>>(hid, wp, bproj, out);
}

// Round 13
// 141.100 us; speedup vs baseline: 1.1332x; 1.0282x over previous
//
#include <hip/hip_runtime.h>
#include <hip/hip_bf16.h>

typedef __attribute__((ext_vector_type(8))) short bf16x8;
typedef __attribute__((ext_vector_type(4))) float f32x4;

__device__ __forceinline__ unsigned short f2bf(float f) {
    union { __hip_bfloat16 h; unsigned short u; } c;
    c.h = __float2bfloat16(f);
    return c.u;
}
__device__ __forceinline__ unsigned int pk2(float lo, float hi) {
    return (unsigned int)f2bf(lo) | ((unsigned int)f2bf(hi) << 16);
}
__device__ __forceinline__ bf16x8 as_bf(uint4 u) {
    union { uint4 a; bf16x8 b; } c; c.a = u; return c.b;
}
__device__ __forceinline__ float bf2f(unsigned short us) {
    return __uint_as_float(((unsigned int)us) << 16);
}
// async global->LDS, 16B/lane; lds dest = wave-uniform base + lane*16 (HW rule)
__device__ __forceinline__ void gload_lds16(const void* g, void* l) {
    __builtin_amdgcn_global_load_lds(
        (const __attribute__((address_space(1))) void*)g,
        (__attribute__((address_space(3))) void*)l, 16, 0, 0);
}

// ===================== prep: x->bf16 + means + gate/poly, weight pack, sym-bias =====================
__global__ __launch_bounds__(256) void prep_kernel(
    const float* __restrict__ x,
    const float* __restrict__ Wq, const float* __restrict__ Wkv, const float* __restrict__ Wproj,
    const float* __restrict__ Wgate, const float* __restrict__ bgate,
    const float* __restrict__ bias_table, const int* __restrict__ rel_index,
    unsigned short* __restrict__ xbf, int use_xbf,
    unsigned short* __restrict__ wq, unsigned short* __restrict__ wk,
    unsigned short* __restrict__ wv, unsigned short* __restrict__ wp,
    float* __restrict__ bsym, float* __restrict__ wpoly)
{
    const int bid = blockIdx.x, t = threadIdx.x;
    if (bid < 1024) {
        __shared__ float mean_s[256];
        __shared__ float gsig[32];
        const float* xb = x + (size_t)bid * 16384;
        float s = 0.f;
        if (use_xbf) {
            unsigned short* xo = xbf + (size_t)bid * 16384;
            #pragma unroll 4
            for (int n = 0; n < 64; n++) { float v = xb[n * 256 + t]; s += v; xo[n * 256 + t] = f2bf(v); }
        } else {
            #pragma unroll 8
            for (int n = 0; n < 64; n++) s += xb[n * 256 + t];
        }
        mean_s[t] = s * (1.f / 64.f);
        __syncthreads();
        if (t < 32) {
            int h = t >> 2, j = t & 3;
            float g = bgate[j];
            #pragma unroll 8
            for (int dd = 0; dd < 32; dd++) g = fmaf(mean_s[h * 32 + dd], Wgate[dd * 4 + j], g);
            gsig[t] = 1.f / (1.f + __expf(-g));
        }
        __syncthreads();
        if (t < 8) {
            float g0 = gsig[t * 4], g1 = gsig[t * 4 + 1], g2 = gsig[t * 4 + 2], g3 = gsig[t * 4 + 3];
            float a = 0.125f * g3, bb = 0.375f * g0, cc = 0.375f * g1, dd = 0.125f * g2;
            float4 o;
            o.x = a + bb + cc + dd;
            o.y = 3.f * a + bb - cc - 3.f * dd;
            o.z = 3.f * a - bb - cc + 3.f * dd;
            o.w = a - bb + cc - dd;
            ((float4*)wpoly)[bid * 8 + t] = o;
        }
    } else if (bid < 2048) {
        // transpose-pack 4 weight matrices to bf16: dst[o][k] = src[k][o]
        int e = (bid - 1024) * 256 + t;
        int m = e >> 16, r = e & 65535, o = r >> 8, kk = r & 255;
        float v; unsigned short* dst;
        if (m == 0)      { v = Wq[kk * 256 + o];        dst = wq; }
        else if (m == 1) { v = Wkv[kk * 512 + o];       dst = wk; }
        else if (m == 2) { v = Wkv[kk * 512 + 256 + o]; dst = wv; }
        else             { v = Wproj[kk * 256 + o];     dst = wp; }
        dst[o * 256 + kk] = f2bf(v);
    } else {
        // symmetric pre-relu positional bias: bsym[h][i*64+j] = (relu(b_ij)+relu(b_ji))/2
        int e = (bid - 2048) * 256 + t;
        int hh = e >> 12, ij = e & 4095;
        int i = ij >> 6, j = ij & 63;
        float bij = bias_table[rel_index[ij] * 8 + hh];
        float bji = bias_table[rel_index[j * 64 + i] * 8 + hh];
        bsym[hh * 4096 + ij] = 0.5f * (fmaxf(bij, 0.f) + fmaxf(bji, 0.f));
    }
}

// ===================== attention core (R9 structure, redundant barriers elided) =====================
// block = one (b,h); 4 waves, QKV role split: w0=q, w1=k, w2/w3=v halves.
// XCD-chunked swizzle: xcd=bid&7 owns b in [xcd*128, xcd*128+128), heads adjacent.
// LDS = 32 KB whole-x staging. launch_bounds(256,4): VGPR cap 128.
// *** Spill law: NEVER raise min-waves above 4 (R5/R7: 200-500 MB scratch).
// *** Split-K staging (R7/R8), 2-head fusion (R11), merged Asq tail (R12) all regressed.
// Barrier ledger (6 of original 8):
//   A: x staged   B: x reads done   C: q/k/vT ready   D: dn ready + q/k reads done
//   F: ua ready   G: ub ready
//   E REMOVED: phase-7 A-frags read only the wave's OWN Ab rows (written by itself
//              in phase 6; same-wave LDS ordering via lgkmcnt); B-operands come from
//              vT (barrier C). No cross-wave Ab read exists.
//   trailing barrier of last AU_ROUND REMOVED: nothing reads LDS afterwards.
// tile regions (bytes): phase1 xs [64 rows][512B] swizzled (32 KB)
// overlay after QKV: Ab/q[0,8K); k[8K,16K); vT[16K,20K); ua[20K,24K); ub[24K,28K); dn f32[64] @28672
template <bool XBF>
__global__ __launch_bounds__(256, 4) void attn_kernel(
    const float* __restrict__ x, const unsigned short* __restrict__ xbf,
    const float* __restrict__ bq, const float* __restrict__ bkv,
    const unsigned short* __restrict__ wq, const unsigned short* __restrict__ wk,
    const unsigned short* __restrict__ wv,
    const float* __restrict__ bsym, const float* __restrict__ wpoly,
    unsigned short* __restrict__ hid)
{
    __shared__ __align__(16) unsigned char tile[32768];
    float* dn = (float*)(tile + 28672);

    const int bid = blockIdx.x;
    const int xcd = bid & 7, idx = bid >> 3;
    const int b = xcd * 128 + (idx >> 3), h = idx & 7;
    const int t = threadIdx.x;
    const int l = t & 63, w = t >> 6;
    const int lr = l & 15, qg = l >> 4;

    const float4 wv4 = ((const float4*)wpoly)[b * 8 + h];

    // ---- hoist weight B-fragments (issued before staging) ----
    const int role = w;                      // 0=q, 1=k, 2=v(d 0..15), 3=v(d 16..31)
    uint4 Bfr0[8], Bfr1[8];
    {
        const unsigned short* wsel = (role == 0) ? wq : (role == 1) ? wk : wv;
        const uint4* Wp = (const uint4*)wsel;
        const int ct0 = (role < 2) ? 0 : (role - 2);
        const int o0 = h * 32 + ct0 * 16 + lr;
        #pragma unroll
        for (int ks = 0; ks < 8; ks++) Bfr0[ks] = Wp[o0 * 32 + ks * 4 + qg];
        if (role < 2) {
            #pragma unroll
            for (int ks = 0; ks < 8; ks++) Bfr1[ks] = Wp[(o0 + 16) * 32 + ks * 4 + qg];
        }
    }

    // ---- phase 1: stage x[b] -> swizzled bf16 LDS ----
    if (XBF) {
        const unsigned short* xb = xbf + (size_t)b * 16384;
        const int rp = l >> 5, u = l & 31;
        #pragma unroll
        for (int i = 0; i < 8; i++) {
            int row = i * 8 + w * 2 + rp;
            int csrc = (u & 24) | ((u & 7) ^ (row & 7));   // inverse of reader swizzle (involution)
            gload_lds16(xb + row * 256 + csrc * 8, tile + (i * 8 + w * 2) * 512);
        }
    } else {
        const float* xb = x + (size_t)b * 16384;
        #pragma unroll
        for (int i = 0; i < 8; i++) {
            int e = t + i * 256;
            int row = e >> 5, c = e & 31;
            const float4* p = (const float4*)(xb + row * 256 + c * 8);
            float4 f0 = p[0], f1 = p[1];
            uint4 u;
            u.x = pk2(f0.x, f0.y); u.y = pk2(f0.z, f0.w);
            u.z = pk2(f1.x, f1.y); u.w = pk2(f1.z, f1.w);
            *(uint4*)(tile + row * 512 + ((c >> 3) << 7) + (((c & 7) ^ (row & 7)) << 4)) = u;
        }
    }

    // bias-init accumulators
    f32x4 acc0[4], acc1[4];
    {
        const int ct0 = (role < 2) ? 0 : (role - 2);
        const int o0 = h * 32 + ct0 * 16 + lr;
        float b0 = (role == 0) ? bq[o0] : (role == 1) ? bkv[o0] : bkv[256 + o0];
        float b1 = (role == 0) ? bq[o0 + 16] : (role == 1) ? bkv[o0 + 16] : 0.f;
        #pragma unroll
        for (int mt = 0; mt < 4; mt++) {
            f32x4 z0 = {b0, b0, b0, b0}; acc0[mt] = z0;
            f32x4 z1 = {b1, b1, b1, b1}; acc1[mt] = z1;
        }
    }
    __syncthreads();   // A: x-tile staged

    // ---- phase 2: QKV MFMA, zero global loads in loop ----
    __builtin_amdgcn_s_setprio(1);
    if (role < 2) {
        #pragma unroll
        for (int mt = 0; mt < 4; mt++) {
            const int rowA = mt * 16 + lr;
            #pragma unroll
            for (int ks = 0; ks < 8; ks++) {
                const int c = ks * 4 + qg;
                bf16x8 af = *(const bf16x8*)(tile + rowA * 512 + ((c >> 3) << 7) + (((c & 7) ^ (rowA & 7)) << 4));
                acc0[mt] = __builtin_amdgcn_mfma_f32_16x16x32_bf16(af, as_bf(Bfr0[ks]), acc0[mt], 0, 0, 0);
                acc1[mt] = __builtin_amdgcn_mfma_f32_16x16x32_bf16(af, as_bf(Bfr1[ks]), acc1[mt], 0, 0, 0);
            }
        }
    } else {
        #pragma unroll
        for (int mt = 0; mt < 4; mt++) {
            const int rowA = mt * 16 + lr;
            #pragma unroll
            for (int ks = 0; ks < 8; ks++) {
                const int c = ks * 4 + qg;
                bf16x8 af = *(const bf16x8*)(tile + rowA * 512 + ((c >> 3) << 7) + (((c & 7) ^ (rowA & 7)) << 4));
                acc0[mt] = __builtin_amdgcn_mfma_f32_16x16x32_bf16(af, as_bf(Bfr0[ks]), acc0[mt], 0, 0, 0);
            }
        }
    }
    __builtin_amdgcn_s_setprio(0);
    __syncthreads();   // B: all reads of x-tile done

    // hoist bsym loads (L2-latency hides under softmax+spill)
    float bsv[4][4];
    {
        const float* bh_ = bsym + h * 4096;
        #pragma unroll
        for (int jt = 0; jt < 4; jt++)
            #pragma unroll
            for (int r = 0; r < 4; r++)
                bsv[jt][r] = bh_[(w * 16 + qg * 4 + r) * 64 + jt * 16 + lr];
    }

    // ---- phase 3: row softmax for q (wave0) / k (wave1), no max-subtraction ----
    if (role < 2) {
        #pragma unroll
        for (int mt = 0; mt < 4; mt++)
            #pragma unroll
            for (int r = 0; r < 4; r++) {
                float e0 = __expf(acc0[mt][r]), e1 = __expf(acc1[mt][r]);
                float s = e0 + e1;
                s += __shfl_xor(s, 1); s += __shfl_xor(s, 2);
                s += __shfl_xor(s, 4); s += __shfl_xor(s, 8);
                float inv = 1.f / s;
                acc0[mt][r] = e0 * inv; acc1[mt][r] = e1 * inv;
            }
    }

    // ---- phase 4: spill q,k (row-major swizzled) and vT ----
    if (role == 0) {
        #pragma unroll
        for (int mt = 0; mt < 4; mt++)
            #pragma unroll
            for (int r = 0; r < 4; r++) {
                int row = mt * 16 + qg * 4 + r;
                int d0 = lr, d1 = 16 + lr;
                *(short*)(tile + row * 128 + (((d0 >> 3) ^ (row & 7)) << 4) + (d0 & 7) * 2) = (short)f2bf(acc0[mt][r]);
                *(short*)(tile + row * 128 + (((d1 >> 3) ^ (row & 7)) << 4) + (d1 & 7) * 2) = (short)f2bf(acc1[mt][r]);
            }
    } else if (role == 1) {
        #pragma unroll
        for (int mt = 0; mt < 4; mt++)
            #pragma unroll
            for (int r = 0; r < 4; r++) {
                int row = mt * 16 + qg * 4 + r;
                int d0 = lr, d1 = 16 + lr;
                *(short*)(tile + 8192 + row * 128 + (((d0 >> 3) ^ (row & 7)) << 4) + (d0 & 7) * 2) = (short)f2bf(acc0[mt][r]);
                *(short*)(tile + 8192 + row * 128 + (((d1 >> 3) ^ (row & 7)) << 4) + (d1 & 7) * 2) = (short)f2bf(acc1[mt][r]);
            }
    } else {
        const int d = (role - 2) * 16 + lr;
        #pragma unroll
        for (int mt = 0; mt < 4; mt++)
            #pragma unroll
            for (int r = 0; r < 4; r++) {
                int row = mt * 16 + qg * 4 + r;
                *(short*)(tile + 16384 + d * 128 + (((row >> 3) ^ (d & 7)) << 4) + (row & 7) * 2) = (short)f2bf(acc0[mt][r]);
            }
    }
    __syncthreads();   // C: q,k,vT readable

    // ---- phase 5: S_sym = (qk^T + (qk^T)^T)/2 + bsym, fused row-sums -> dn ----
    float sv[4][4];
    float dnv[4];
    {
        const int swz = (qg ^ (lr & 7)) << 4;
        bf16x8 aqf = *(const bf16x8*)(tile + (w * 16 + lr) * 128 + swz);
        bf16x8 akf = *(const bf16x8*)(tile + 8192 + (w * 16 + lr) * 128 + swz);
        float rs[4] = {0.f, 0.f, 0.f, 0.f};
        __builtin_amdgcn_s_setprio(1);
        #pragma unroll
        for (int jt = 0; jt < 4; jt++) {
            bf16x8 bqf = *(const bf16x8*)(tile + (jt * 16 + lr) * 128 + swz);
            bf16x8 bkf = *(const bf16x8*)(tile + 8192 + (jt * 16 + lr) * 128 + swz);
            f32x4 qk = {0.f, 0.f, 0.f, 0.f}, kq = {0.f, 0.f, 0.f, 0.f};
            qk = __builtin_amdgcn_mfma_f32_16x16x32_bf16(aqf, bkf, qk, 0, 0, 0);
            kq = __builtin_amdgcn_mfma_f32_16x16x32_bf16(akf, bqf, kq, 0, 0, 0);
            #pragma unroll
            for (int r = 0; r < 4; r++) {
                float v = 0.5f * (qk[r] + kq[r]) + bsv[jt][r];
                sv[jt][r] = v;
                rs[r] += v;
            }
        }
        __builtin_amdgcn_s_setprio(0);
        #pragma unroll
        for (int r = 0; r < 4; r++) {
            float s = rs[r];
            s += __shfl_xor(s, 1); s += __shfl_xor(s, 2);
            s += __shfl_xor(s, 4); s += __shfl_xor(s, 8);
            dnv[r] = (s > 0.f) ? rsqrtf(s) : s;
        }
        if (lr == 0) {
            int base = w * 16 + qg * 4;
            dn[base + 0] = dnv[0]; dn[base + 1] = dnv[1];
            dn[base + 2] = dnv[2]; dn[base + 3] = dnv[3];
        }
    }
    __syncthreads();   // D: dn ready; q/k reads done -> Ab may overwrite q region

    // ---- y init: y = w0 * v (vT stable since C; overlaps phase 6) ----
    const float w0c = wv4.x, w1c = wv4.y, w2c = wv4.z, w3c = wv4.w;
    f32x4 y[2];
    #pragma unroll
    for (int ct = 0; ct < 2; ct++)
        #pragma unroll
        for (int r = 0; r < 4; r++) {
            int row = w * 16 + qg * 4 + r;
            int d = ct * 16 + lr;
            unsigned short us = *(unsigned short*)(tile + 16384 + d * 128 + (((row >> 3) ^ (d & 7)) << 4) + (row & 7) * 2);
            y[ct][r] = w0c * bf2f(us);
        }

    // ---- phase 6: normalize in-register, spill Ab bf16 (overlays q region) ----
    {
        float dnj[4];
        #pragma unroll
        for (int jt = 0; jt < 4; jt++) dnj[jt] = dn[jt * 16 + lr];
        #pragma unroll
        for (int jt = 0; jt < 4; jt++)
            #pragma unroll
            for (int r = 0; r < 4; r++) {
                int i = w * 16 + qg * 4 + r, j = jt * 16 + lr;
                *(short*)(tile + i * 128 + (((j >> 3) ^ (i & 7)) << 4) + (j & 7) * 2)
                    = (short)f2bf(sv[jt][r] * dnv[r] * dnj[jt]);
            }
    }
    // (barrier E removed — AU rounds read only this wave's own Ab rows)

    // ---- phases 7-9: y += w1 Av + w2 A^2 v + w3 A^3 v ----
#define AU_ROUND(SRC, DST, WC, WRITE) {                                                          \
    f32x4 u0 = {0.f,0.f,0.f,0.f}, u1 = {0.f,0.f,0.f,0.f};                                        \
    __builtin_amdgcn_s_setprio(1);                                                               \
    _Pragma("unroll")                                                                            \
    for (int ks2 = 0; ks2 < 2; ks2++) {                                                          \
        int c = ks2 * 4 + qg;                                                                    \
        bf16x8 af = *(const bf16x8*)(tile + (w * 16 + lr) * 128 + ((c ^ (lr & 7)) << 4));        \
        bf16x8 b0 = *(const bf16x8*)(tile + (SRC) + lr * 128 + ((c ^ (lr & 7)) << 4));           \
        bf16x8 b1 = *(const bf16x8*)(tile + (SRC) + (16 + lr) * 128 + ((c ^ (lr & 7)) << 4));    \
        u0 = __builtin_amdgcn_mfma_f32_16x16x32_bf16(af, b0, u0, 0, 0, 0);                       \
        u1 = __builtin_amdgcn_mfma_f32_16x16x32_bf16(af, b1, u1, 0, 0, 0);                       \
    }                                                                                            \
    __builtin_amdgcn_s_setprio(0);                                                               \
    y[0] += (WC) * u0; y[1] += (WC) * u1;                                                        \
    if (WRITE) {                                                                                 \
        _Pragma("unroll")                                                                        \
        for (int r = 0; r < 4; r++) {                                                            \
            int i = w * 16 + qg * 4 + r;                                                         \
            *(short*)(tile + (DST) + lr * 128 + (((i >> 3) ^ (lr & 7)) << 4) + (i & 7) * 2) = (short)f2bf(u0[r]); \
            *(short*)(tile + (DST) + (16 + lr) * 128 + (((i >> 3) ^ (lr & 7)) << 4) + (i & 7) * 2) = (short)f2bf(u1[r]); \
        }                                                                                        \
        __syncthreads();                                                                         \
    }                                                                                            \
}
    AU_ROUND(16384, 20480, w1c, 1)   // u1 = A v   -> ua ; barrier F
    AU_ROUND(20480, 24576, w2c, 1)   // u2 = A u1  -> ub ; barrier G
    AU_ROUND(24576, 0,     w3c, 0)   // u3 = A u2  ; no trailing barrier
#undef AU_ROUND

    // ---- write hidden bf16 ----
    #pragma unroll
    for (int ct = 0; ct < 2; ct++)
        #pragma unroll
        for (int r = 0; r < 4; r++) {
            int row = w * 16 + qg * 4 + r;
            int col = h * 32 + ct * 16 + lr;
            hid[((size_t)b * 64 + row) * 256 + col] = f2bf(y[ct][r]);
        }
}

// ===================== output projection: 128 x 256 tile, hidden read once =====================
__global__ __launch_bounds__(256) void proj_kernel(
    const unsigned short* __restrict__ hidden,
    const unsigned short* __restrict__ wp,
    const float* __restrict__ bproj,
    float* __restrict__ out)
{
    __shared__ __align__(16) unsigned char atile[65536];
    const int rb = blockIdx.x;
    const int t = threadIdx.x, l = t & 63, w = t >> 6;
    const int lr = l & 15, qg = l >> 4;

    const unsigned short* hb = hidden + (size_t)rb * 128 * 256;
    {
        const int rp = l >> 5, u = l & 31;
        #pragma unroll
        for (int i = 0; i < 16; i++) {
            int row = i * 8 + w * 2 + rp;
            int csrc = (u & 24) | ((u & 7) ^ (row & 7));
            gload_lds16(hb + row * 256 + csrc * 8, atile + (i * 8 + w * 2) * 512);
        }
    }
    float bzv[16];
    #pragma unroll
    for (int ct = 0; ct < 16; ct++) bzv[ct] = bproj[ct * 16 + lr];
    __syncthreads();

    // hoist A fragments: 2 row-tiles x 8 k-steps
    bf16x8 af[2][8];
    #pragma unroll
    for (int rt = 0; rt < 2; rt++) {
        int row = w * 32 + rt * 16 + lr;
        #pragma unroll
        for (int ks = 0; ks < 8; ks++) {
            int c = ks * 4 + qg;
            af[rt][ks] = *(const bf16x8*)(atile + row * 512 + (((c & 24) | ((c & 7) ^ (row & 7))) << 4));
        }
    }

    const uint4* WP = (const uint4*)wp;
    #pragma unroll 2
    for (int ct = 0; ct < 16; ct++) {
        f32x4 a0 = {0.f, 0.f, 0.f, 0.f}, a1 = {0.f, 0.f, 0.f, 0.f};
        #pragma unroll
        for (int ks = 0; ks < 8; ks++) {
            bf16x8 bf = as_bf(WP[(ct * 16 + lr) * 32 + ks * 4 + qg]);
            a0 = __builtin_amdgcn_mfma_f32_16x16x32_bf16(af[0][ks], bf, a0, 0, 0, 0);
            a1 = __builtin_amdgcn_mfma_f32_16x16x32_bf16(af[1][ks], bf, a1, 0, 0, 0);
        }
        int colg = ct * 16 + lr;
        float bz = bzv[ct];
        #pragma unroll
        for (int r = 0; r < 4; r++) {
            int rowg = rb * 128 + w * 32 + qg * 4 + r;
            out[(size_t)rowg * 256 + colg] = a0[r] + bz;
            out[(size_t)(rowg + 16) * 256 + colg] = a1[r] + bz;
        }
    }
}

extern "C" void kernel_launch(void* const* d_in, const int* in_sizes, int n_in,
                              void* d_out, int out_size, void* d_ws, size_t ws_size,
                              hipStream_t stream) {
    const float* x          = (const float*)d_in[0];
    const float* Wq         = (const float*)d_in[1];
    const float* bq         = (const float*)d_in[2];
    const float* Wkv        = (const float*)d_in[3];
    const float* bkv        = (const float*)d_in[4];
    const float* Wgate      = (const float*)d_in[5];
    const float* bgate      = (const float*)d_in[6];
    const float* Wproj      = (const float*)d_in[7];
    const float* bproj      = (const float*)d_in[8];
    const float* bias_table = (const float*)d_in[9];
    const int*   rel_index  = (const int*)d_in[10];
    float* out = (float*)d_out;
    unsigned char* wsb = (unsigned char*)d_ws;

    // ws layout (bytes)
    const size_t HID   = 0;                    // 33,554,432 (hidden bf16)
    const size_t WQo   = 33554432;             // 131072 each
    const size_t WKo   = WQo + 131072;
    const size_t WVo   = WKo + 131072;
    const size_t WPo   = WVo + 131072;
    const size_t BIASo = WPo + 131072;         // 131072 (bsym f32 [8][64][64])
    const size_t WPOLY = BIASo + 131072;       // 131072
    const size_t XBFo  = WPOLY + 131072;       // 33,554,432 (x bf16) — optional
    const int use_xbf  = (ws_size >= XBFo + 33554432ull) ? 1 : 0;

    unsigned short* hid = (unsigned short*)(wsb + HID);
    unsigned short* wq  = (unsigned short*)(wsb + WQo);
    unsigned short* wk  = (unsigned short*)(wsb + WKo);
    unsigned short* wv  = (unsigned short*)(wsb + WVo);
    unsigned short* wp  = (unsigned short*)(wsb + WPo);
    float* bsym  = (float*)(wsb + BIASo);
    float* wpoly = (float*)(wsb + WPOLY);
    unsigned short* xbf = (unsigned short*)(wsb + XBFo);

    prep_kernel<<<dim3(2176), dim3(256), 0, stream>>>(
        x, Wq, Wkv, Wproj, Wgate, bgate, bias_table, rel_index,
        xbf, use_xbf, wq, wk, wv, wp, bsym, wpoly);
    if (use_xbf)
        attn_kernel<true><<<dim3(8192), dim3(256), 0, stream>>>(
            x, xbf, bq, bkv, wq, wk, wv, bsym, wpoly, hid);
    else
        attn_kernel<false><<<dim3(8192), dim3(256), 0, stream>>>(
            x, xbf, bq, bkv, wq, wk, wv, bsym, wpoly, hid);
    proj_kernel<<<dim3(512), dim3(256), 0, stream>>>(hid, wp, bproj, out);
}